// Round 1
// 406.535 us; speedup vs baseline: 1.3135x; 1.3135x over previous
//
#include <hip/hip_runtime.h>
#include <hip/hip_bf16.h>

// Problem dims (fixed): B*N=32768, IN=256, H=256, I=64, A=64, NA=32, NH=256
#define BN_ 32768

using bf16 = __hip_bfloat16;
typedef __bf16 v8bf __attribute__((ext_vector_type(8)));
typedef unsigned short v8us __attribute__((ext_vector_type(8)));
typedef float v4f __attribute__((ext_vector_type(4)));

__device__ __forceinline__ float b2f(bf16 x) { return __bfloat162float(x); }
__device__ __forceinline__ bf16 f2b(float x) { return __float2bfloat16(x); }
__device__ __forceinline__ unsigned short f2bu(float x) {
  bf16 h = __float2bfloat16(x);
  return *reinterpret_cast<unsigned short*>(&h);
}
__device__ __forceinline__ float bu2f(unsigned short u) {
  union { unsigned int i; float f; } x;
  x.i = ((unsigned int)u) << 16;
  return x.f;
}
__device__ __forceinline__ void gl_lds16(const void* g, void* l) {
  __builtin_amdgcn_global_load_lds(
      (const __attribute__((address_space(1))) void*)g,
      (__attribute__((address_space(3))) void*)l, 16, 0, 0);
}
template <int CF>
__device__ __forceinline__ void cstore(void* C, size_t off, float v) {
  if constexpr (CF) ((float*)C)[off] = v;
  else ((bf16*)C)[off] = f2b(v);
}

// C = epilogue(Acat @ Bcat^T + bias). CF: 1 -> C fp32, 0 -> C bf16.
// Acat: cols [0,KS) from A1, [KS,K) from A2 (KS=0 -> A1 only). A1M/A2M: 1=fp32, 0=bf16.
// Bcat: canonical bf16 weights; rows n; cols [0,KSB) from B1, rest from B2.
// ACT: 0 none, 1 relu, 3 fused GRU epilogue (requires TM=128,TN=128,WR=2,WC=2,CF=1):
//   h = (1-z)*tanh(acc+bias + r*e1) + z*e2 ; r=sig(e0[.,col]), z=sig(e0[.,256+col]);
//   e1 (fp32) may alias C (each element read before written by the same thread); e2 fp32.
//   ACT=3 stages the acc tile through LDS so the GRU pass is fully coalesced+vectorized.
template <int TM, int TN, int WR, int WC, int ACT, int A1M, int A2M, int KS, int KSB, int CF>
__global__ __launch_bounds__(256) void gemm_bt(
    const void* __restrict__ A1, int lda1, const void* __restrict__ A2, int lda2,
    const bf16* __restrict__ B1, const bf16* __restrict__ B2, int ldb,
    const float* __restrict__ bias, void* C, int ldc, int K,
    const bf16* __restrict__ e0, const float* e1, const float* __restrict__ e2) {
  constexpr int BK = 64;
  __shared__ __align__(16) unsigned short As[TM * BK];
  __shared__ __align__(16) unsigned short Bs[TN * BK];
  const int tid = threadIdx.x;
  const int wv = tid >> 6;
  const int lane = tid & 63;
  const int bm = blockIdx.x * TM;
  const int bn = blockIdx.y * TN;
  constexpr int WM = TM / WR, WN = TN / WC;
  constexpr int FM = WM / 16, FN = WN / 16;
  const int wm0 = (wv % WR) * WM;
  const int wn0 = (wv / WR) * WN;

  v4f acc[FM][FN];
  const v4f vzero = {0.f, 0.f, 0.f, 0.f};
  for (int i = 0; i < FM; ++i)
    for (int j = 0; j < FN; ++j) acc[i][j] = vzero;

  const int lrow = lane >> 3;       // row within 8-row chunk
  const int lcol = (lane & 7) * 8;  // col offset, 8 elems per lane
  const int mr = lane & 15;         // MFMA m/n index
  const int kq = (lane >> 4) * 8;   // MFMA k offset

  for (int k0 = 0; k0 < K; k0 += BK) {
    {  // ---- stage A tile ----
      const bool useA1 = (KS == 0) || (k0 < KS);
      const void* Ap = useA1 ? A1 : A2;
      const int lda = useA1 ? lda1 : lda2;
      const int ka = useA1 ? k0 : k0 - KS;
      const bool f32 = useA1 ? (A1M == 1) : (A2M == 1);
      if (f32) {
        const float* Af = (const float*)Ap;
        for (int ch = wv; ch < TM / 8; ch += 4) {
          const float* s = Af + (size_t)(bm + ch * 8 + lrow) * lda + ka + lcol;
          float4 x0 = *(const float4*)s;
          float4 x1 = *(const float4*)(s + 4);
          v8us d;
          d[0]=f2bu(x0.x); d[1]=f2bu(x0.y); d[2]=f2bu(x0.z); d[3]=f2bu(x0.w);
          d[4]=f2bu(x1.x); d[5]=f2bu(x1.y); d[6]=f2bu(x1.z); d[7]=f2bu(x1.w);
          *(v8us*)(As + ch * 8 * BK + lane * 8) = d;
        }
      } else {
        const unsigned short* Ab = (const unsigned short*)Ap;
        for (int ch = wv; ch < TM / 8; ch += 4)
          gl_lds16(Ab + (size_t)(bm + ch * 8 + lrow) * lda + ka + lcol,
                   As + ch * 8 * BK);
      }
    }
    {  // ---- stage B tile (canonical bf16) ----
      const bool useB1 = (KSB == 0) || (k0 < KSB);
      const bf16* Bp = useB1 ? B1 : B2;
      const int kb = useB1 ? k0 : k0 - KSB;
      for (int ch = wv; ch < TN / 8; ch += 4)
        gl_lds16((const unsigned short*)Bp + (size_t)(bn + ch * 8 + lrow) * ldb + kb + lcol,
                 Bs + ch * 8 * BK);
    }
    __syncthreads();
#pragma unroll
    for (int kk = 0; kk < BK; kk += 32) {
      v8bf af[FM], bfr[FN];
#pragma unroll
      for (int i = 0; i < FM; ++i)
        af[i] = *(const v8bf*)(As + (wm0 + i * 16 + mr) * BK + kk + kq);
#pragma unroll
      for (int j = 0; j < FN; ++j)
        bfr[j] = *(const v8bf*)(Bs + (wn0 + j * 16 + mr) * BK + kk + kq);
#pragma unroll
      for (int i = 0; i < FM; ++i)
#pragma unroll
        for (int j = 0; j < FN; ++j)
          acc[i][j] = __builtin_amdgcn_mfma_f32_16x16x32_bf16(af[i], bfr[j],
                                                              acc[i][j], 0, 0, 0);
    }
    __syncthreads();
  }
  const int crow = (lane >> 4) * 4;

  if constexpr (ACT == 3) {
    // ---- GRU epilogue: LDS-staged, coalesced, vectorized ----
    // Tile is 128x128 (4 waves in 2x2). Stage one 64-col half at a time into
    // a padded fp32 LDS buffer, then all 256 threads sweep it row-linearly.
    __shared__ float Ep[128 * 65];
    const int myhalf = wn0 >> 6;  // which col-half this wave's acc lands in
    const int c4 = (tid & 15) * 4;
#pragma unroll
    for (int h = 0; h < 2; ++h) {
      __syncthreads();
      if (myhalf == h) {
#pragma unroll
        for (int i = 0; i < FM; ++i)
#pragma unroll
          for (int j = 0; j < FN; ++j)
#pragma unroll
            for (int r = 0; r < 4; ++r)
              Ep[(wm0 + i * 16 + crow + r) * 65 + j * 16 + mr] = acc[i][j][r];
      }
      __syncthreads();
#pragma unroll
      for (int it = 0; it < 8; ++it) {
        const int row = (tid >> 4) + it * 16;
        const int grow = bm + row;
        const int gcol = bn + h * 64 + c4;
        const unsigned short* g1p =
            (const unsigned short*)e0 + (size_t)grow * 512 + gcol;
        const ushort4 r4 = *(const ushort4*)g1p;          // r-gate preacts (bf16)
        const ushort4 z4 = *(const ushort4*)(g1p + 256);  // z-gate preacts (bf16)
        const float4 hn4 = *(const float4*)(e1 + (size_t)grow * 256 + gcol);
        const float4 hp4 = *(const float4*)(e2 + (size_t)grow * 256 + gcol);
        const float rv[4] = {bu2f(r4.x), bu2f(r4.y), bu2f(r4.z), bu2f(r4.w)};
        const float zv[4] = {bu2f(z4.x), bu2f(z4.y), bu2f(z4.z), bu2f(z4.w)};
        const float hnv[4] = {hn4.x, hn4.y, hn4.z, hn4.w};
        const float hpv[4] = {hp4.x, hp4.y, hp4.z, hp4.w};
        float vo[4];
#pragma unroll
        for (int u = 0; u < 4; ++u) {
          float v = Ep[row * 65 + c4 + u] + bias[gcol + u];
          float rr = 1.f / (1.f + expf(-rv[u]));
          float zz = 1.f / (1.f + expf(-zv[u]));
          float nn = tanhf(v + rr * hnv[u]);
          vo[u] = (1.f - zz) * nn + zz * hpv[u];
        }
        *(float4*)((float*)C + (size_t)grow * ldc + gcol) =
            make_float4(vo[0], vo[1], vo[2], vo[3]);
      }
    }
  } else {
#pragma unroll
    for (int j = 0; j < FN; ++j) {
      const int gcol = bn + wn0 + j * 16 + mr;
      const float bv = bias[gcol];
#pragma unroll
      for (int i = 0; i < FM; ++i) {
#pragma unroll
        for (int r = 0; r < 4; ++r) {
          const int grow = bm + wm0 + i * 16 + crow + r;
          size_t off = (size_t)grow * ldc + gcol;
          float v = acc[i][j][r] + bv;
          if (ACT == 1) v = v > 0.f ? v : 0.f;
          cstore<CF>(C, off, v);
        }
      }
    }
  }
}

// Canonicalize (fp32 in): weights -> bf16 blob WF, biases -> fp32 blob FB; zero BN stats.
// WF element map: fc1_w@0[65536] w_ih@65536[196608] w_hh@262144[196608]
//   W1P@458752[81920 (256x320, in1_w padded 288->320)] in2_w@540672[32768]
//   WQK@573440[8192 (128x64 [wq;wk])] wv_w@581632[20480] fc2_w@602112[10240]
// FB float map: fc1_b@0[256] BRZ@256[512 = b_ih_rz+b_hh_rz] BIN@768[256] BHN@1024[256]
//   in1_b@1280[256] in2_b@1536[128] BQK@1664[128] wv_b@1792[64] fc2_b@1856[32]
//   bn_g@1888[256] bn_b@2144[256] (gap) stats@2560[1024, zeroed]
__global__ void conv_all(
    const float* fc1_w, const float* w_ih, const float* w_hh, const float* in1_w,
    const float* in2_w, const float* wq_w, const float* wk_w, const float* wv_w,
    const float* fc2_w, const float* fc1_b, const float* b_ih, const float* b_hh,
    const float* in1_b, const float* in2_b, const float* wq_b, const float* wk_b,
    const float* wv_b, const float* fc2_b, const float* bn_g, const float* bn_b,
    bf16* __restrict__ WF, float* __restrict__ FB) {
  int idx = blockIdx.x * 256 + threadIdx.x;
  if (idx < 612352) {
    float v;
    if (idx < 65536) v = fc1_w[idx];
    else if (idx < 262144) v = w_ih[idx - 65536];
    else if (idx < 458752) v = w_hh[idx - 262144];
    else if (idx < 540672) {
      int j = idx - 458752, r = j / 320, c = j % 320;
      v = (c < 288) ? in1_w[r * 288 + c] : 0.f;
    } else if (idx < 573440) v = in2_w[idx - 540672];
    else if (idx < 581632) {
      int j = idx - 573440, r = j >> 6, c = j & 63;
      v = (r < 64) ? wq_w[r * 64 + c] : wk_w[(r - 64) * 64 + c];
    } else if (idx < 602112) v = wv_w[idx - 581632];
    else v = fc2_w[idx - 602112];
    WF[idx] = f2b(v);
  } else if (idx < 615936) {
    int j = idx - 612352;  // 0..3583
    float v;
    if (j < 256) v = fc1_b[j];
    else if (j < 768) v = b_ih[j - 256] + b_hh[j - 256];
    else if (j < 1024) v = b_ih[512 + j - 768];
    else if (j < 1280) v = b_hh[512 + j - 1024];
    else if (j < 1536) v = in1_b[j - 1280];
    else if (j < 1664) v = in2_b[j - 1536];
    else if (j < 1792) { int c = j - 1664; v = (c < 64) ? wq_b[c] : wk_b[c - 64]; }
    else if (j < 1856) v = wv_b[j - 1792];
    else if (j < 1888) v = fc2_b[j - 1856];
    else if (j < 2144) v = bn_g[j - 1888];
    else if (j < 2400) v = bn_b[j - 2144];
    else v = 0.f;  // gap + stats region zeroed
    FB[j] = v;
  }
}

// LAP (32768x64 bf16) = [last_actions | zeros]
__global__ void pack_la(const float* __restrict__ la, bf16* __restrict__ lap) {
  int idx = blockIdx.x * 256 + threadIdx.x;  // BN_*64
  int row = idx >> 6, c = idx & 63;
  lap[idx] = f2b((c < 32) ? la[(size_t)row * 32 + c] : 0.f);
}

__global__ void bn_reduce(const bf16* __restrict__ Z1, float* __restrict__ stats) {
  int col = threadIdx.x;
  float s = 0.f, q = 0.f;
  for (int r = blockIdx.x; r < BN_; r += 256) {
    float v = b2f(Z1[(size_t)r * 256 + col]);
    s += v; q += v * v;
  }
  atomicAdd(&stats[col], s);
  atomicAdd(&stats[256 + col], q);
}

__global__ void bn_finalize(const float* __restrict__ g, const float* __restrict__ b,
                            float* __restrict__ stats) {
  int c = threadIdx.x;
  float mean = stats[c] * (1.f / 32768.f);
  float var = stats[256 + c] * (1.f / 32768.f) - mean * mean;
  var = fmaxf(var, 0.f);
  float sc = g[c] * rsqrtf(var + 1e-5f);
  stats[512 + c] = sc;
  stats[768 + c] = b[c] - mean * sc;
}

__global__ void bn_leaky(const bf16* __restrict__ Z1, const float* __restrict__ stats,
                         bf16* __restrict__ zt) {
  int idx = blockIdx.x * 256 + threadIdx.x;
  int col = idx & 255;
  float v = b2f(Z1[idx]) * stats[512 + col] + stats[768 + col];
  zt[idx] = f2b(v > 0.f ? v : 0.01f * v);
}

__global__ void make_intent(const float* __restrict__ ie, const float* __restrict__ eps,
                            float* __restrict__ intent) {
  int idx = blockIdx.x * 256 + threadIdx.x;  // BN_*64
  int row = idx >> 6, c = idx & 63;
  float mean = ie[(size_t)row * 128 + c];
  float sd = fmaxf(expf(ie[(size_t)row * 128 + 64 + c]), 0.002f);
  intent[idx] = mean + eps[idx] * sd;
}

__global__ __launch_bounds__(64) void attn(const bf16* __restrict__ QK,
                                           const bf16* __restrict__ Vv,
                                           bf16* __restrict__ comb) {
  __shared__ float q[8][65], k[8][65], v[8][65];
  __shared__ float al[8][8];
  int b = blockIdx.x, t = threadIdx.x;
  size_t rb = (size_t)b * 8;
  for (int u = 0; u < 8; ++u) {
    q[u][t] = b2f(QK[(rb + u) * 128 + t]);
    k[u][t] = b2f(QK[(rb + u) * 128 + 64 + t]);
    v[u][t] = b2f(Vv[(rb + u) * 64 + t]);
  }
  __syncthreads();
  int i = t >> 3, j = t & 7;
  float s = 0.f;
#pragma unroll
  for (int a = 0; a < 64; ++a) s += q[i][a] * k[j][a];
  s *= 0.125f;
  if (i == j) s = -1e9f;
  float m = s;
  m = fmaxf(m, __shfl_xor(m, 1, 8));
  m = fmaxf(m, __shfl_xor(m, 2, 8));
  m = fmaxf(m, __shfl_xor(m, 4, 8));
  float e = expf(s - m);
  float sum = e;
  sum += __shfl_xor(sum, 1, 8);
  sum += __shfl_xor(sum, 2, 8);
  sum += __shfl_xor(sum, 4, 8);
  al[i][j] = e / sum;
  __syncthreads();
  int a0 = (t & 7) * 8;
  for (int u = 0; u < 8; ++u) {
    float o = 0.f;
#pragma unroll
    for (int jj = 0; jj < 8; ++jj) o += al[i][jj] * v[jj][a0 + u];
    comb[(rb + i) * 64 + a0 + u] = f2b(o);
  }
}

extern "C" void kernel_launch(void* const* d_in, const int* in_sizes, int n_in,
                              void* d_out, int out_size, void* d_ws, size_t ws_size,
                              hipStream_t stream) {
  (void)in_sizes; (void)n_in; (void)out_size; (void)ws_size;
  const float* inputs = (const float*)d_in[0];
  const float* last_actions = (const float*)d_in[1];
  const float* hidden = (const float*)d_in[2];
  const float* eps = (const float*)d_in[3];

  // d_out is FP32 (reference output dtype)
  float* out = (float*)d_out;
  float* out_lq = out;             // 32768x32
  float* out_h = out + 1048576;    // 32768x256 (HN scratch pre-GRU, then h)
  float* out_it = out + 9437184;   // 32768x64
  float* out_ie = out + 11534336;  // 32768x128

  // ---- workspace: peak ~51.6 MB ----
  char* ws = (char*)d_ws;
  bf16* X    = (bf16*)(ws + 0);            // 16 MiB, dead after GRU i_n gemm
  bf16* G1   = (bf16*)(ws + 16777216);     // 32 MiB, dead after GRU i_n gemm
  bf16* LAP  = (bf16*)(ws + 16777216);     // 4 MiB over dead G1
  bf16* ZT   = (bf16*)(ws + 20971520);     // 16 MiB over dead G1
  bf16* Z1   = (bf16*)(ws + 0);            // 16 MiB over dead X
  bf16* QK   = (bf16*)(ws + 0);            // 8 MiB over dead Z1
  bf16* V    = (bf16*)(ws + 8388608);      // 4 MiB over dead Z1
  bf16* COMB = (bf16*)(ws + 12582912);     // 4 MiB over dead Z1
  float* FB  = (float*)(ws + 50331648);    // 3584 floats @ 48 MiB mark
  bf16*  WF  = (bf16*)(ws + 50348032);     // 612352 bf16
  float* stats = FB + 2560;

  conv_all<<<2406, 256, 0, stream>>>(
      (const float*)d_in[4], (const float*)d_in[6], (const float*)d_in[7],
      (const float*)d_in[10], (const float*)d_in[14], (const float*)d_in[16],
      (const float*)d_in[18], (const float*)d_in[20], (const float*)d_in[22],
      (const float*)d_in[5], (const float*)d_in[8], (const float*)d_in[9],
      (const float*)d_in[11], (const float*)d_in[15], (const float*)d_in[17],
      (const float*)d_in[19], (const float*)d_in[21], (const float*)d_in[23],
      (const float*)d_in[12], (const float*)d_in[13], WF, FB);

  // x = relu(inputs @ fc1_w^T + fc1_b)   [A fp32 -> X bf16]
  gemm_bt<128, 128, 2, 2, 1, 1, 0, 0, 0, 0><<<dim3(256, 2), 256, 0, stream>>>(
      inputs, 256, nullptr, 0, WF + 0, nullptr, 256, FB + 0,
      X, 256, 256, nullptr, nullptr, nullptr);
  // G1 = [x | h] @ [w_ih_rz | w_hh_rz]^T + (b_ih_rz + b_hh_rz)   -> bf16
  gemm_bt<128, 128, 2, 2, 0, 0, 1, 256, 256, 0><<<dim3(256, 4), 256, 0, stream>>>(
      X, 256, hidden, 256, WF + 65536, WF + 262144, 256, FB + 256,
      G1, 512, 512, nullptr, nullptr, nullptr);
  // HN (in out_h region, fp32) = h @ w_hh_n^T + b_hh_n
  gemm_bt<128, 128, 2, 2, 0, 1, 0, 0, 0, 1><<<dim3(256, 2), 256, 0, stream>>>(
      hidden, 256, nullptr, 0, WF + 262144 + 512 * 256, nullptr, 256, FB + 1024,
      out_h, 256, 256, nullptr, nullptr, nullptr);
  // out_h (fp32) = GRU(i_n = x @ w_ih_n^T + b_ih_n ; G1, HN(=out_h), hprev)
  gemm_bt<128, 128, 2, 2, 3, 0, 0, 0, 0, 1><<<dim3(256, 2), 256, 0, stream>>>(
      X, 256, nullptr, 0, WF + 65536 + 512 * 256, nullptr, 256, FB + 768,
      out_h, 256, 256, G1, out_h, hidden);

  pack_la<<<8192, 256, 0, stream>>>(last_actions, LAP);
  // z1 = [h(fp32) | la_pad(bf16)] @ W1P^T + in1_b   (K=320) -> Z1 bf16
  gemm_bt<128, 128, 2, 2, 0, 1, 0, 256, 0, 0><<<dim3(256, 2), 256, 0, stream>>>(
      out_h, 256, LAP, 64, WF + 458752, nullptr, 320, FB + 1280,
      Z1, 256, 320, nullptr, nullptr, nullptr);
  bn_reduce<<<256, 256, 0, stream>>>(Z1, stats);
  bn_finalize<<<1, 256, 0, stream>>>(FB + 1888, FB + 2144, stats);
  bn_leaky<<<32768, 256, 0, stream>>>(Z1, stats, ZT);
  // intent_embed (fp32) = zt @ in2_w^T + in2_b
  gemm_bt<128, 128, 2, 2, 0, 0, 0, 0, 0, 1><<<dim3(256, 1), 256, 0, stream>>>(
      ZT, 256, nullptr, 0, WF + 540672, nullptr, 256, FB + 1536,
      out_ie, 128, 256, nullptr, nullptr, nullptr);
  make_intent<<<8192, 256, 0, stream>>>(out_ie, eps, out_it);
  // q|k = intent(fp32) @ [wq;wk]^T -> QK bf16
  gemm_bt<128, 128, 2, 2, 0, 1, 0, 0, 0, 0><<<dim3(256, 1), 256, 0, stream>>>(
      out_it, 64, nullptr, 0, WF + 573440, nullptr, 64, FB + 1664,
      QK, 128, 64, nullptr, nullptr, nullptr);
  // v = [intent(fp32) | h(fp32)] @ wv^T   (K=320) -> V bf16
  gemm_bt<128, 64, 4, 1, 0, 1, 1, 64, 0, 0><<<dim3(256, 1), 256, 0, stream>>>(
      out_it, 64, out_h, 256, WF + 581632, nullptr, 320, FB + 1792,
      V, 64, 320, nullptr, nullptr, nullptr);
  attn<<<4096, 64, 0, stream>>>(QK, V, COMB);
  // local_Q (fp32) = [h(fp32) | combined(bf16)] @ fc2^T   (K=320)
  gemm_bt<128, 32, 4, 1, 0, 1, 0, 256, 0, 1><<<dim3(256, 1), 256, 0, stream>>>(
      out_h, 256, COMB, 64, WF + 602112, nullptr, 320, FB + 1856,
      out_lq, 32, 320, nullptr, nullptr, nullptr);
}

// Round 2
// 403.360 us; speedup vs baseline: 1.3239x; 1.0079x over previous
//
#include <hip/hip_runtime.h>
#include <hip/hip_bf16.h>

// Problem dims (fixed): B*N=32768, IN=256, H=256, I=64, A=64, NA=32, NH=256
#define BN_ 32768

using bf16 = __hip_bfloat16;
typedef __bf16 v8bf __attribute__((ext_vector_type(8)));
typedef unsigned short v8us __attribute__((ext_vector_type(8)));
typedef float v4f __attribute__((ext_vector_type(4)));

__device__ __forceinline__ float b2f(bf16 x) { return __bfloat162float(x); }
__device__ __forceinline__ bf16 f2b(float x) { return __float2bfloat16(x); }
__device__ __forceinline__ unsigned short f2bu(float x) {
  bf16 h = __float2bfloat16(x);
  return *reinterpret_cast<unsigned short*>(&h);
}
__device__ __forceinline__ float bu2f(unsigned short u) {
  union { unsigned int i; float f; } x;
  x.i = ((unsigned int)u) << 16;
  return x.f;
}
__device__ __forceinline__ void gl_lds16(const void* g, void* l) {
  __builtin_amdgcn_global_load_lds(
      (const __attribute__((address_space(1))) void*)g,
      (__attribute__((address_space(3))) void*)l, 16, 0, 0);
}
template <int CF>
__device__ __forceinline__ void cstore(void* C, size_t off, float v) {
  if constexpr (CF) ((float*)C)[off] = v;
  else ((bf16*)C)[off] = f2b(v);
}

// C = epilogue(Acat @ Bcat^T + bias). CF: 1 -> C fp32, 0 -> C bf16.
// Acat: cols [0,KS) from A1, [KS,K) from A2 (KS=0 -> A1 only). A1M/A2M: 1=fp32, 0=bf16.
// Bcat: canonical bf16 weights; rows n; cols [0,KSB) from B1, rest from B2.
// ACT: 0 none, 1 relu, 3 fused GRU epilogue (requires TM=128,TN=128,WR=2,WC=2,CF=1):
//   h = (1-z)*tanh(acc+bias + r*e1) + z*e2 ; r=sig(e0[.,col]), z=sig(e0[.,256+col]);
//   e1 (fp32) may alias C (each element read before written by the same thread);
//   e2: fp32 if E2B==0, bf16 if E2B==1.
// All blocks are XCD-swizzled so same-M (A-sharing) blocks co-locate on one XCD L2.
template <int TM, int TN, int WR, int WC, int ACT, int A1M, int A2M, int KS, int KSB,
          int CF, int E2B = 0>
__global__ __launch_bounds__(256) void gemm_bt(
    const void* __restrict__ A1, int lda1, const void* __restrict__ A2, int lda2,
    const bf16* __restrict__ B1, const bf16* __restrict__ B2, int ldb,
    const float* __restrict__ bias, void* C, int ldc, int K,
    const bf16* __restrict__ e0, const float* e1, const void* __restrict__ e2) {
  constexpr int BK = 64;
  __shared__ __align__(16) unsigned short As[TM * BK];
  __shared__ __align__(16) unsigned short Bs[TN * BK];
  const int tid = threadIdx.x;
  const int wv = tid >> 6;
  const int lane = tid & 63;

  // ---- XCD-aware bijective swizzle: hardware assigns linear id round-robin to
  // 8 XCDs; remap so each XCD owns a contiguous chunk of work ids, and work ids
  // enumerate N fastest -> same-A blocks are adjacent on one XCD.
  int w;
  {
    const int nbx = gridDim.x, nby = gridDim.y;
    const int f = blockIdx.y * nbx + blockIdx.x;
    const int nwg = nbx * nby;
    const int q = nwg >> 3, r = nwg & 7;
    const int xcd = f & 7, l = f >> 3;
    if (r == 0) w = xcd * q + l;
    else w = (xcd < r ? xcd * (q + 1) : r * (q + 1) + (xcd - r) * q) + l;
  }
  const int bm = (w / gridDim.y) * TM;
  const int bn = (w % gridDim.y) * TN;

  constexpr int WM = TM / WR, WN = TN / WC;
  constexpr int FM = WM / 16, FN = WN / 16;
  const int wm0 = (wv % WR) * WM;
  const int wn0 = (wv / WR) * WN;

  v4f acc[FM][FN];
  const v4f vzero = {0.f, 0.f, 0.f, 0.f};
  for (int i = 0; i < FM; ++i)
    for (int j = 0; j < FN; ++j) acc[i][j] = vzero;

  const int lrow = lane >> 3;       // row within 8-row chunk
  const int lcol = (lane & 7) * 8;  // col offset, 8 elems per lane
  const int mr = lane & 15;         // MFMA m/n index
  const int kq = (lane >> 4) * 8;   // MFMA k offset

  for (int k0 = 0; k0 < K; k0 += BK) {
    {  // ---- stage A tile ----
      const bool useA1 = (KS == 0) || (k0 < KS);
      const void* Ap = useA1 ? A1 : A2;
      const int lda = useA1 ? lda1 : lda2;
      const int ka = useA1 ? k0 : k0 - KS;
      const bool f32 = useA1 ? (A1M == 1) : (A2M == 1);
      if (f32) {
        const float* Af = (const float*)Ap;
        for (int ch = wv; ch < TM / 8; ch += 4) {
          const float* s = Af + (size_t)(bm + ch * 8 + lrow) * lda + ka + lcol;
          float4 x0 = *(const float4*)s;
          float4 x1 = *(const float4*)(s + 4);
          v8us d;
          d[0]=f2bu(x0.x); d[1]=f2bu(x0.y); d[2]=f2bu(x0.z); d[3]=f2bu(x0.w);
          d[4]=f2bu(x1.x); d[5]=f2bu(x1.y); d[6]=f2bu(x1.z); d[7]=f2bu(x1.w);
          *(v8us*)(As + ch * 8 * BK + lane * 8) = d;
        }
      } else {
        const unsigned short* Ab = (const unsigned short*)Ap;
        for (int ch = wv; ch < TM / 8; ch += 4)
          gl_lds16(Ab + (size_t)(bm + ch * 8 + lrow) * lda + ka + lcol,
                   As + ch * 8 * BK);
      }
    }
    {  // ---- stage B tile (canonical bf16) ----
      const bool useB1 = (KSB == 0) || (k0 < KSB);
      const bf16* Bp = useB1 ? B1 : B2;
      const int kb = useB1 ? k0 : k0 - KSB;
      for (int ch = wv; ch < TN / 8; ch += 4)
        gl_lds16((const unsigned short*)Bp + (size_t)(bn + ch * 8 + lrow) * ldb + kb + lcol,
                 Bs + ch * 8 * BK);
    }
    __syncthreads();
#pragma unroll
    for (int kk = 0; kk < BK; kk += 32) {
      v8bf af[FM], bfr[FN];
#pragma unroll
      for (int i = 0; i < FM; ++i)
        af[i] = *(const v8bf*)(As + (wm0 + i * 16 + mr) * BK + kk + kq);
#pragma unroll
      for (int j = 0; j < FN; ++j)
        bfr[j] = *(const v8bf*)(Bs + (wn0 + j * 16 + mr) * BK + kk + kq);
#pragma unroll
      for (int i = 0; i < FM; ++i)
#pragma unroll
        for (int j = 0; j < FN; ++j)
          acc[i][j] = __builtin_amdgcn_mfma_f32_16x16x32_bf16(af[i], bfr[j],
                                                              acc[i][j], 0, 0, 0);
    }
    __syncthreads();
  }
  const int crow = (lane >> 4) * 4;

  if constexpr (ACT == 3) {
    // ---- GRU epilogue: LDS-staged, coalesced, vectorized ----
    // Pad 68 (not 65): keeps rows 16B-aligned and quarter-wave banks {0,16,0,16}
    // -> free 2-way instead of 4-way conflicts.
    __shared__ float Ep[128 * 68];
    const int myhalf = wn0 >> 6;  // which col-half this wave's acc lands in
    const int c4 = (tid & 15) * 4;
#pragma unroll
    for (int h = 0; h < 2; ++h) {
      __syncthreads();
      if (myhalf == h) {
#pragma unroll
        for (int i = 0; i < FM; ++i)
#pragma unroll
          for (int j = 0; j < FN; ++j)
#pragma unroll
            for (int r = 0; r < 4; ++r)
              Ep[(wm0 + i * 16 + crow + r) * 68 + j * 16 + mr] = acc[i][j][r];
      }
      __syncthreads();
#pragma unroll
      for (int it = 0; it < 8; ++it) {
        const int row = (tid >> 4) + it * 16;
        const int grow = bm + row;
        const int gcol = bn + h * 64 + c4;
        const unsigned short* g1p =
            (const unsigned short*)e0 + (size_t)grow * 512 + gcol;
        const ushort4 r4 = *(const ushort4*)g1p;          // r-gate preacts (bf16)
        const ushort4 z4 = *(const ushort4*)(g1p + 256);  // z-gate preacts (bf16)
        const float4 hn4 = *(const float4*)(e1 + (size_t)grow * 256 + gcol);
        float hpv[4];
        if constexpr (E2B) {
          const ushort4 hp4 = *(const ushort4*)((const unsigned short*)e2 +
                                                (size_t)grow * 256 + gcol);
          hpv[0] = bu2f(hp4.x); hpv[1] = bu2f(hp4.y);
          hpv[2] = bu2f(hp4.z); hpv[3] = bu2f(hp4.w);
        } else {
          const float4 hp4 = *(const float4*)((const float*)e2 +
                                              (size_t)grow * 256 + gcol);
          hpv[0] = hp4.x; hpv[1] = hp4.y; hpv[2] = hp4.z; hpv[3] = hp4.w;
        }
        const float rv[4] = {bu2f(r4.x), bu2f(r4.y), bu2f(r4.z), bu2f(r4.w)};
        const float zv[4] = {bu2f(z4.x), bu2f(z4.y), bu2f(z4.z), bu2f(z4.w)};
        const float hnv[4] = {hn4.x, hn4.y, hn4.z, hn4.w};
        float vo[4];
#pragma unroll
        for (int u = 0; u < 4; ++u) {
          float v = Ep[row * 68 + c4 + u] + bias[gcol + u];
          float rr = 1.f / (1.f + expf(-rv[u]));
          float zz = 1.f / (1.f + expf(-zv[u]));
          float nn = tanhf(v + rr * hnv[u]);
          vo[u] = (1.f - zz) * nn + zz * hpv[u];
        }
        *(float4*)((float*)C + (size_t)grow * ldc + gcol) =
            make_float4(vo[0], vo[1], vo[2], vo[3]);
      }
    }
  } else {
#pragma unroll
    for (int j = 0; j < FN; ++j) {
      const int gcol = bn + wn0 + j * 16 + mr;
      const float bv = bias[gcol];
#pragma unroll
      for (int i = 0; i < FM; ++i) {
#pragma unroll
        for (int r = 0; r < 4; ++r) {
          const int grow = bm + wm0 + i * 16 + crow + r;
          size_t off = (size_t)grow * ldc + gcol;
          float v = acc[i][j][r] + bv;
          if (ACT == 1) v = v > 0.f ? v : 0.f;
          cstore<CF>(C, off, v);
        }
      }
    }
  }
}

// Canonicalize (fp32 in): weights -> bf16 blob WF, biases -> fp32 blob FB; zero BN stats.
// WF element map: fc1_w@0[65536] w_ih@65536[196608] w_hh@262144[196608]
//   W1P@458752[81920 (256x320, in1_w padded 288->320)] in2_w@540672[32768]
//   WQK@573440[8192 (128x64 [wq;wk])] wv_w@581632[20480] fc2_w@602112[10240]
// FB float map: fc1_b@0[256] BRZ@256[512 = b_ih_rz+b_hh_rz] BIN@768[256] BHN@1024[256]
//   in1_b@1280[256] in2_b@1536[128] BQK@1664[128] wv_b@1792[64] fc2_b@1856[32]
//   bn_g@1888[256] bn_b@2144[256] (gap) stats@2560[1024, zeroed]
__global__ void conv_all(
    const float* fc1_w, const float* w_ih, const float* w_hh, const float* in1_w,
    const float* in2_w, const float* wq_w, const float* wk_w, const float* wv_w,
    const float* fc2_w, const float* fc1_b, const float* b_ih, const float* b_hh,
    const float* in1_b, const float* in2_b, const float* wq_b, const float* wk_b,
    const float* wv_b, const float* fc2_b, const float* bn_g, const float* bn_b,
    bf16* __restrict__ WF, float* __restrict__ FB) {
  int idx = blockIdx.x * 256 + threadIdx.x;
  if (idx < 612352) {
    float v;
    if (idx < 65536) v = fc1_w[idx];
    else if (idx < 262144) v = w_ih[idx - 65536];
    else if (idx < 458752) v = w_hh[idx - 262144];
    else if (idx < 540672) {
      int j = idx - 458752, r = j / 320, c = j % 320;
      v = (c < 288) ? in1_w[r * 288 + c] : 0.f;
    } else if (idx < 573440) v = in2_w[idx - 540672];
    else if (idx < 581632) {
      int j = idx - 573440, r = j >> 6, c = j & 63;
      v = (r < 64) ? wq_w[r * 64 + c] : wk_w[(r - 64) * 64 + c];
    } else if (idx < 602112) v = wv_w[idx - 581632];
    else v = fc2_w[idx - 602112];
    WF[idx] = f2b(v);
  } else if (idx < 615936) {
    int j = idx - 612352;  // 0..3583
    float v;
    if (j < 256) v = fc1_b[j];
    else if (j < 768) v = b_ih[j - 256] + b_hh[j - 256];
    else if (j < 1024) v = b_ih[512 + j - 768];
    else if (j < 1280) v = b_hh[512 + j - 1024];
    else if (j < 1536) v = in1_b[j - 1280];
    else if (j < 1664) v = in2_b[j - 1536];
    else if (j < 1792) { int c = j - 1664; v = (c < 64) ? wq_b[c] : wk_b[c - 64]; }
    else if (j < 1856) v = wv_b[j - 1792];
    else if (j < 1888) v = fc2_b[j - 1856];
    else if (j < 2144) v = bn_g[j - 1888];
    else if (j < 2400) v = bn_b[j - 2144];
    else v = 0.f;  // gap + stats region zeroed
    FB[j] = v;
  }
}

// Vectorized fp32 -> bf16 copy (8 elems/thread).
__global__ void f2b_copy(const float* __restrict__ s, bf16* __restrict__ d) {
  int i = blockIdx.x * 256 + threadIdx.x;
  const float4 a = ((const float4*)s)[i * 2];
  const float4 b = ((const float4*)s)[i * 2 + 1];
  v8us o;
  o[0]=f2bu(a.x); o[1]=f2bu(a.y); o[2]=f2bu(a.z); o[3]=f2bu(a.w);
  o[4]=f2bu(b.x); o[5]=f2bu(b.y); o[6]=f2bu(b.z); o[7]=f2bu(b.w);
  ((v8us*)d)[i] = o;
}

// LAP (32768x64 bf16) = [last_actions | zeros]
__global__ void pack_la(const float* __restrict__ la, bf16* __restrict__ lap) {
  int idx = blockIdx.x * 256 + threadIdx.x;  // BN_*64
  int row = idx >> 6, c = idx & 63;
  lap[idx] = f2b((c < 32) ? la[(size_t)row * 32 + c] : 0.f);
}

__global__ void bn_reduce(const bf16* __restrict__ Z1, float* __restrict__ stats) {
  int col = threadIdx.x;
  float s = 0.f, q = 0.f;
  for (int r = blockIdx.x; r < BN_; r += 256) {
    float v = b2f(Z1[(size_t)r * 256 + col]);
    s += v; q += v * v;
  }
  atomicAdd(&stats[col], s);
  atomicAdd(&stats[256 + col], q);
}

__global__ void bn_finalize(const float* __restrict__ g, const float* __restrict__ b,
                            float* __restrict__ stats) {
  int c = threadIdx.x;
  float mean = stats[c] * (1.f / 32768.f);
  float var = stats[256 + c] * (1.f / 32768.f) - mean * mean;
  var = fmaxf(var, 0.f);
  float sc = g[c] * rsqrtf(var + 1e-5f);
  stats[512 + c] = sc;
  stats[768 + c] = b[c] - mean * sc;
}

__global__ void bn_leaky(const bf16* __restrict__ Z1, const float* __restrict__ stats,
                         bf16* __restrict__ zt) {
  int idx = blockIdx.x * 256 + threadIdx.x;
  int col = idx & 255;
  float v = b2f(Z1[idx]) * stats[512 + col] + stats[768 + col];
  zt[idx] = f2b(v > 0.f ? v : 0.01f * v);
}

__global__ void make_intent(const float* __restrict__ ie, const float* __restrict__ eps,
                            float* __restrict__ intent) {
  int idx = blockIdx.x * 256 + threadIdx.x;  // BN_*64
  int row = idx >> 6, c = idx & 63;
  float mean = ie[(size_t)row * 128 + c];
  float sd = fmaxf(expf(ie[(size_t)row * 128 + 64 + c]), 0.002f);
  intent[idx] = mean + eps[idx] * sd;
}

__global__ __launch_bounds__(64) void attn(const bf16* __restrict__ QK,
                                           const bf16* __restrict__ Vv,
                                           bf16* __restrict__ comb) {
  __shared__ float q[8][65], k[8][65], v[8][65];
  __shared__ float al[8][8];
  int b = blockIdx.x, t = threadIdx.x;
  size_t rb = (size_t)b * 8;
  for (int u = 0; u < 8; ++u) {
    q[u][t] = b2f(QK[(rb + u) * 128 + t]);
    k[u][t] = b2f(QK[(rb + u) * 128 + 64 + t]);
    v[u][t] = b2f(Vv[(rb + u) * 64 + t]);
  }
  __syncthreads();
  int i = t >> 3, j = t & 7;
  float s = 0.f;
#pragma unroll
  for (int a = 0; a < 64; ++a) s += q[i][a] * k[j][a];
  s *= 0.125f;
  if (i == j) s = -1e9f;
  float m = s;
  m = fmaxf(m, __shfl_xor(m, 1, 8));
  m = fmaxf(m, __shfl_xor(m, 2, 8));
  m = fmaxf(m, __shfl_xor(m, 4, 8));
  float e = expf(s - m);
  float sum = e;
  sum += __shfl_xor(sum, 1, 8);
  sum += __shfl_xor(sum, 2, 8);
  sum += __shfl_xor(sum, 4, 8);
  al[i][j] = e / sum;
  __syncthreads();
  int a0 = (t & 7) * 8;
  for (int u = 0; u < 8; ++u) {
    float o = 0.f;
#pragma unroll
    for (int jj = 0; jj < 8; ++jj) o += al[i][jj] * v[jj][a0 + u];
    comb[(rb + i) * 64 + a0 + u] = f2b(o);
  }
}

extern "C" void kernel_launch(void* const* d_in, const int* in_sizes, int n_in,
                              void* d_out, int out_size, void* d_ws, size_t ws_size,
                              hipStream_t stream) {
  (void)in_sizes; (void)n_in; (void)out_size; (void)ws_size;
  const float* inputs = (const float*)d_in[0];
  const float* last_actions = (const float*)d_in[1];
  const float* hidden = (const float*)d_in[2];
  const float* eps = (const float*)d_in[3];

  // d_out is FP32 (reference output dtype)
  float* out = (float*)d_out;
  float* out_lq = out;             // 32768x32
  float* out_h = out + 1048576;    // 32768x256 (HN scratch pre-GRU, then h)
  float* out_it = out + 9437184;   // 32768x64
  float* out_ie = out + 11534336;  // 32768x128

  // HB = bf16(hidden), scratch in the out_ie region (dead until in2 gemm).
  bf16* HB = (bf16*)(out + 11534336);  // 16 MiB as bf16 (32768x256)

  // ---- workspace: peak ~51.6 MB ----
  char* ws = (char*)d_ws;
  bf16* X    = (bf16*)(ws + 0);            // 16 MiB, dead after GRU i_n gemm
  bf16* G1   = (bf16*)(ws + 16777216);     // 32 MiB, dead after GRU i_n gemm
  bf16* LAP  = (bf16*)(ws + 16777216);     // 4 MiB over dead G1
  bf16* ZT   = (bf16*)(ws + 20971520);     // 16 MiB over dead G1
  bf16* Z1   = (bf16*)(ws + 0);            // 16 MiB over dead X
  bf16* QK   = (bf16*)(ws + 0);            // 8 MiB over dead Z1
  bf16* V    = (bf16*)(ws + 8388608);      // 4 MiB over dead Z1
  bf16* COMB = (bf16*)(ws + 12582912);     // 4 MiB over dead Z1
  float* FB  = (float*)(ws + 50331648);    // 3584 floats @ 48 MiB mark
  bf16*  WF  = (bf16*)(ws + 50348032);     // 612352 bf16
  float* stats = FB + 2560;

  conv_all<<<2406, 256, 0, stream>>>(
      (const float*)d_in[4], (const float*)d_in[6], (const float*)d_in[7],
      (const float*)d_in[10], (const float*)d_in[14], (const float*)d_in[16],
      (const float*)d_in[18], (const float*)d_in[20], (const float*)d_in[22],
      (const float*)d_in[5], (const float*)d_in[8], (const float*)d_in[9],
      (const float*)d_in[11], (const float*)d_in[15], (const float*)d_in[17],
      (const float*)d_in[19], (const float*)d_in[21], (const float*)d_in[23],
      (const float*)d_in[12], (const float*)d_in[13], WF, FB);

  // HB = bf16(hidden)
  f2b_copy<<<4096, 256, 0, stream>>>(hidden, HB);

  // x = relu(inputs @ fc1_w^T + fc1_b)   [A fp32 -> X bf16]
  gemm_bt<128, 128, 2, 2, 1, 1, 0, 0, 0, 0><<<dim3(256, 2), 256, 0, stream>>>(
      inputs, 256, nullptr, 0, WF + 0, nullptr, 256, FB + 0,
      X, 256, 256, nullptr, nullptr, nullptr);
  // G1 = [x | hb] @ [w_ih_rz | w_hh_rz]^T + (b_ih_rz + b_hh_rz)   -> bf16
  gemm_bt<128, 128, 2, 2, 0, 0, 0, 256, 256, 0><<<dim3(256, 4), 256, 0, stream>>>(
      X, 256, HB, 256, WF + 65536, WF + 262144, 256, FB + 256,
      G1, 512, 512, nullptr, nullptr, nullptr);
  // HN (in out_h region, fp32) = hb @ w_hh_n^T + b_hh_n
  gemm_bt<128, 128, 2, 2, 0, 0, 0, 0, 0, 1><<<dim3(256, 2), 256, 0, stream>>>(
      HB, 256, nullptr, 0, WF + 262144 + 512 * 256, nullptr, 256, FB + 1024,
      out_h, 256, 256, nullptr, nullptr, nullptr);
  // out_h (fp32) = GRU(i_n = x @ w_ih_n^T + b_ih_n ; G1, HN(=out_h), hprev=HB bf16)
  gemm_bt<128, 128, 2, 2, 3, 0, 0, 0, 0, 1, 1><<<dim3(256, 2), 256, 0, stream>>>(
      X, 256, nullptr, 0, WF + 65536 + 512 * 256, nullptr, 256, FB + 768,
      out_h, 256, 256, G1, out_h, HB);

  pack_la<<<8192, 256, 0, stream>>>(last_actions, LAP);
  // z1 = [h(fp32) | la_pad(bf16)] @ W1P^T + in1_b   (K=320) -> Z1 bf16
  gemm_bt<128, 128, 2, 2, 0, 1, 0, 256, 0, 0><<<dim3(256, 2), 256, 0, stream>>>(
      out_h, 256, LAP, 64, WF + 458752, nullptr, 320, FB + 1280,
      Z1, 256, 320, nullptr, nullptr, nullptr);
  bn_reduce<<<256, 256, 0, stream>>>(Z1, stats);
  bn_finalize<<<1, 256, 0, stream>>>(FB + 1888, FB + 2144, stats);
  bn_leaky<<<32768, 256, 0, stream>>>(Z1, stats, ZT);
  // intent_embed (fp32) = zt @ in2_w^T + in2_b
  gemm_bt<128, 128, 2, 2, 0, 0, 0, 0, 0, 1><<<dim3(256, 1), 256, 0, stream>>>(
      ZT, 256, nullptr, 0, WF + 540672, nullptr, 256, FB + 1536,
      out_ie, 128, 256, nullptr, nullptr, nullptr);
  make_intent<<<8192, 256, 0, stream>>>(out_ie, eps, out_it);
  // q|k = intent(fp32) @ [wq;wk]^T -> QK bf16
  gemm_bt<128, 128, 2, 2, 0, 1, 0, 0, 0, 0><<<dim3(256, 1), 256, 0, stream>>>(
      out_it, 64, nullptr, 0, WF + 573440, nullptr, 64, FB + 1664,
      QK, 128, 64, nullptr, nullptr, nullptr);
  // v = [intent(fp32) | h(fp32)] @ wv^T   (K=320) -> V bf16
  gemm_bt<128, 64, 4, 1, 0, 1, 1, 64, 0, 0><<<dim3(256, 1), 256, 0, stream>>>(
      out_it, 64, out_h, 256, WF + 581632, nullptr, 320, FB + 1792,
      V, 64, 320, nullptr, nullptr, nullptr);
  attn<<<4096, 64, 0, stream>>>(QK, V, COMB);
  // local_Q (fp32) = [h(fp32) | combined(bf16)] @ fc2^T   (K=320)
  gemm_bt<128, 32, 4, 1, 0, 1, 0, 256, 0, 1><<<dim3(256, 1), 256, 0, stream>>>(
      out_h, 256, COMB, 64, WF + 602112, nullptr, 320, FB + 1856,
      out_lq, 32, 320, nullptr, nullptr, nullptr);
}

// Round 3
// 373.555 us; speedup vs baseline: 1.4295x; 1.0798x over previous
//
#include <hip/hip_runtime.h>
#include <hip/hip_bf16.h>

// Problem dims (fixed): B*N=32768, IN=256, H=256, I=64, A=64, NA=32, NH=256
#define BN_ 32768

using bf16 = __hip_bfloat16;
typedef __bf16 v8bf __attribute__((ext_vector_type(8)));
typedef unsigned short v8us __attribute__((ext_vector_type(8)));
typedef float v4f __attribute__((ext_vector_type(4)));

__device__ __forceinline__ float b2f(bf16 x) { return __bfloat162float(x); }
__device__ __forceinline__ bf16 f2b(float x) { return __float2bfloat16(x); }
__device__ __forceinline__ unsigned short f2bu(float x) {
  bf16 h = __float2bfloat16(x);
  return *reinterpret_cast<unsigned short*>(&h);
}
__device__ __forceinline__ float bu2f(unsigned short u) {
  union { unsigned int i; float f; } x;
  x.i = ((unsigned int)u) << 16;
  return x.f;
}
__device__ __forceinline__ void gl_lds16(const void* g, void* l) {
  __builtin_amdgcn_global_load_lds(
      (const __attribute__((address_space(1))) void*)g,
      (__attribute__((address_space(3))) void*)l, 16, 0, 0);
}
// Fast transcendentals: |err| ~1e-6 relative, exact at +-inf. Fine vs bf16 noise.
__device__ __forceinline__ float fsig(float x) { return 1.f / (1.f + __expf(-x)); }
__device__ __forceinline__ float ftanh(float x) {
  return 1.f - 2.f / (__expf(2.f * x) + 1.f);
}
template <int CF>
__device__ __forceinline__ void cstore(void* C, size_t off, float v) {
  if constexpr (CF) ((float*)C)[off] = v;
  else ((bf16*)C)[off] = f2b(v);
}
// XCD-aware bijective swizzle: same-A blocks adjacent on one XCD L2.
__device__ __forceinline__ int xcd_swz() {
  const int nbx = gridDim.x, nby = gridDim.y;
  const int f = blockIdx.y * nbx + blockIdx.x;
  const int nwg = nbx * nby;
  const int q = nwg >> 3, r = nwg & 7;
  const int xcd = f & 7, l = f >> 3;
  if (r == 0) return xcd * q + l;
  return (xcd < r ? xcd * (q + 1) : r * (q + 1) + (xcd - r) * q) + l;
}

// C = epilogue(Acat @ Bcat^T + bias). CF: 1 -> C fp32, 0 -> C bf16.
// Acat: cols [0,KS) from A1, [KS,K) from A2 (KS=0 -> A1 only). A1M/A2M: 1=fp32, 0=bf16.
// Bcat: canonical bf16 weights; rows n; cols [0,KSB) from B1, rest from B2.
// ACT: 0 none, 1 relu.
template <int TM, int TN, int WR, int WC, int ACT, int A1M, int A2M, int KS, int KSB,
          int CF>
__global__ __launch_bounds__(256) void gemm_bt(
    const void* __restrict__ A1, int lda1, const void* __restrict__ A2, int lda2,
    const bf16* __restrict__ B1, const bf16* __restrict__ B2, int ldb,
    const float* __restrict__ bias, void* C, int ldc, int K) {
  constexpr int BK = 64;
  __shared__ __align__(16) unsigned short As[TM * BK];
  __shared__ __align__(16) unsigned short Bs[TN * BK];
  const int tid = threadIdx.x;
  const int wv = tid >> 6;
  const int lane = tid & 63;
  const int w = xcd_swz();
  const int bm = (w / gridDim.y) * TM;
  const int bn = (w % gridDim.y) * TN;

  constexpr int WM = TM / WR, WN = TN / WC;
  constexpr int FM = WM / 16, FN = WN / 16;
  const int wm0 = (wv % WR) * WM;
  const int wn0 = (wv / WR) * WN;

  v4f acc[FM][FN];
  const v4f vzero = {0.f, 0.f, 0.f, 0.f};
  for (int i = 0; i < FM; ++i)
    for (int j = 0; j < FN; ++j) acc[i][j] = vzero;

  const int lrow = lane >> 3;       // row within 8-row chunk
  const int lcol = (lane & 7) * 8;  // col offset, 8 elems per lane
  const int mr = lane & 15;         // MFMA m/n index
  const int kq = (lane >> 4) * 8;   // MFMA k offset

  for (int k0 = 0; k0 < K; k0 += BK) {
    {  // ---- stage A tile ----
      const bool useA1 = (KS == 0) || (k0 < KS);
      const void* Ap = useA1 ? A1 : A2;
      const int lda = useA1 ? lda1 : lda2;
      const int ka = useA1 ? k0 : k0 - KS;
      const bool f32 = useA1 ? (A1M == 1) : (A2M == 1);
      if (f32) {
        const float* Af = (const float*)Ap;
        for (int ch = wv; ch < TM / 8; ch += 4) {
          const float* s = Af + (size_t)(bm + ch * 8 + lrow) * lda + ka + lcol;
          float4 x0 = *(const float4*)s;
          float4 x1 = *(const float4*)(s + 4);
          v8us d;
          d[0]=f2bu(x0.x); d[1]=f2bu(x0.y); d[2]=f2bu(x0.z); d[3]=f2bu(x0.w);
          d[4]=f2bu(x1.x); d[5]=f2bu(x1.y); d[6]=f2bu(x1.z); d[7]=f2bu(x1.w);
          *(v8us*)(As + ch * 8 * BK + lane * 8) = d;
        }
      } else {
        const unsigned short* Ab = (const unsigned short*)Ap;
        for (int ch = wv; ch < TM / 8; ch += 4)
          gl_lds16(Ab + (size_t)(bm + ch * 8 + lrow) * lda + ka + lcol,
                   As + ch * 8 * BK);
      }
    }
    {  // ---- stage B tile (canonical bf16) ----
      const bool useB1 = (KSB == 0) || (k0 < KSB);
      const bf16* Bp = useB1 ? B1 : B2;
      const int kb = useB1 ? k0 : k0 - KSB;
      for (int ch = wv; ch < TN / 8; ch += 4)
        gl_lds16((const unsigned short*)Bp + (size_t)(bn + ch * 8 + lrow) * ldb + kb + lcol,
                 Bs + ch * 8 * BK);
    }
    __syncthreads();
#pragma unroll
    for (int kk = 0; kk < BK; kk += 32) {
      v8bf af[FM], bfr[FN];
#pragma unroll
      for (int i = 0; i < FM; ++i)
        af[i] = *(const v8bf*)(As + (wm0 + i * 16 + mr) * BK + kk + kq);
#pragma unroll
      for (int j = 0; j < FN; ++j)
        bfr[j] = *(const v8bf*)(Bs + (wn0 + j * 16 + mr) * BK + kk + kq);
#pragma unroll
      for (int i = 0; i < FM; ++i)
#pragma unroll
        for (int j = 0; j < FN; ++j)
          acc[i][j] = __builtin_amdgcn_mfma_f32_16x16x32_bf16(af[i], bfr[j],
                                                              acc[i][j], 0, 0, 0);
    }
    __syncthreads();
  }
  const int crow = (lane >> 4) * 4;
#pragma unroll
  for (int j = 0; j < FN; ++j) {
    const int gcol = bn + wn0 + j * 16 + mr;
    const float bv = bias[gcol];
#pragma unroll
    for (int i = 0; i < FM; ++i) {
#pragma unroll
      for (int r = 0; r < 4; ++r) {
        const int grow = bm + wm0 + i * 16 + crow + r;
        size_t off = (size_t)grow * ldc + gcol;
        float v = acc[i][j][r] + bv;
        if (ACT == 1) v = v > 0.f ? v : 0.f;
        cstore<CF>(C, off, v);
      }
    }
  }
}

// Fused GRU: dual-accumulator gemm computing i_n = X @ Win^T and hn = HB @ Whn^T
// in one pass, then h = (1-z)*tanh(i_n+b_in + r*(hn+b_hn)) + z*h_prev with
// r/z = sigmoid(G1 preacts). TM=128, TN=128, 4 waves (2x2). K=256 fixed.
// LDS: staging (4x16KB) aliased with two 128x68 fp32 epilogue tiles (68KB block).
__global__ __launch_bounds__(256) void gru_fused(
    const bf16* __restrict__ X, const bf16* __restrict__ HB,
    const bf16* __restrict__ Win, const bf16* __restrict__ Whn,
    const float* __restrict__ FBp, const bf16* __restrict__ G1,
    float* __restrict__ Hout) {
  constexpr int BK = 64;
  __shared__ __align__(16) char smem[69632];
  unsigned short* AsX = (unsigned short*)smem;     // 16 KB
  unsigned short* AsH = AsX + 8192;                // 16 KB
  unsigned short* Bin = AsH + 8192;                // 16 KB
  unsigned short* Bhn = Bin + 8192;                // 16 KB
  float* Ein = (float*)smem;                       // 128*68 fp32 = 34816 B
  float* Ehn = (float*)(smem + 34816);             // 128*68 fp32

  const int tid = threadIdx.x;
  const int wv = tid >> 6;
  const int lane = tid & 63;
  const int w = xcd_swz();
  const int bm = (w / gridDim.y) * 128;
  const int bn = (w % gridDim.y) * 128;
  const int wm0 = (wv & 1) * 64;
  const int wn0 = (wv >> 1) * 64;

  v4f ain[4][4], ahn[4][4];
  const v4f vzero = {0.f, 0.f, 0.f, 0.f};
  for (int i = 0; i < 4; ++i)
    for (int j = 0; j < 4; ++j) { ain[i][j] = vzero; ahn[i][j] = vzero; }

  const int lrow = lane >> 3;
  const int lcol = (lane & 7) * 8;
  const int mr = lane & 15;
  const int kq = (lane >> 4) * 8;

  for (int k0 = 0; k0 < 256; k0 += BK) {
    for (int ch = wv; ch < 16; ch += 4) {
      const size_t aoff = (size_t)(bm + ch * 8 + lrow) * 256 + k0 + lcol;
      gl_lds16((const unsigned short*)X + aoff, AsX + ch * 8 * BK);
      gl_lds16((const unsigned short*)HB + aoff, AsH + ch * 8 * BK);
      const size_t boff = (size_t)(bn + ch * 8 + lrow) * 256 + k0 + lcol;
      gl_lds16((const unsigned short*)Win + boff, Bin + ch * 8 * BK);
      gl_lds16((const unsigned short*)Whn + boff, Bhn + ch * 8 * BK);
    }
    __syncthreads();
#pragma unroll
    for (int kk = 0; kk < BK; kk += 32) {
      v8bf ax[4], ah[4], bi[4], bh[4];
#pragma unroll
      for (int i = 0; i < 4; ++i) {
        ax[i] = *(const v8bf*)(AsX + (wm0 + i * 16 + mr) * BK + kk + kq);
        ah[i] = *(const v8bf*)(AsH + (wm0 + i * 16 + mr) * BK + kk + kq);
      }
#pragma unroll
      for (int j = 0; j < 4; ++j) {
        bi[j] = *(const v8bf*)(Bin + (wn0 + j * 16 + mr) * BK + kk + kq);
        bh[j] = *(const v8bf*)(Bhn + (wn0 + j * 16 + mr) * BK + kk + kq);
      }
#pragma unroll
      for (int i = 0; i < 4; ++i)
#pragma unroll
        for (int j = 0; j < 4; ++j) {
          ain[i][j] = __builtin_amdgcn_mfma_f32_16x16x32_bf16(ax[i], bi[j],
                                                              ain[i][j], 0, 0, 0);
          ahn[i][j] = __builtin_amdgcn_mfma_f32_16x16x32_bf16(ah[i], bh[j],
                                                              ahn[i][j], 0, 0, 0);
        }
    }
    __syncthreads();
  }

  const int crow = (lane >> 4) * 4;
  const int myhalf = wn0 >> 6;
  const int c4 = (tid & 15) * 4;
#pragma unroll
  for (int h = 0; h < 2; ++h) {
    __syncthreads();
    if (myhalf == h) {
#pragma unroll
      for (int i = 0; i < 4; ++i)
#pragma unroll
        for (int j = 0; j < 4; ++j)
#pragma unroll
          for (int r = 0; r < 4; ++r) {
            const int idx = (wm0 + i * 16 + crow + r) * 68 + j * 16 + mr;
            Ein[idx] = ain[i][j][r];
            Ehn[idx] = ahn[i][j][r];
          }
    }
    __syncthreads();
#pragma unroll
    for (int it = 0; it < 8; ++it) {
      const int row = (tid >> 4) + it * 16;
      const int grow = bm + row;
      const int gcol = bn + h * 64 + c4;
      const unsigned short* g1p = (const unsigned short*)G1 + (size_t)grow * 512 + gcol;
      const ushort4 r4 = *(const ushort4*)g1p;
      const ushort4 z4 = *(const ushort4*)(g1p + 256);
      const ushort4 hp4 = *(const ushort4*)((const unsigned short*)HB +
                                            (size_t)grow * 256 + gcol);
      const float4 ei = *(const float4*)(Ein + row * 68 + c4);
      const float4 eh = *(const float4*)(Ehn + row * 68 + c4);
      const float4 bin4 = *(const float4*)(FBp + 768 + gcol);
      const float4 bhn4 = *(const float4*)(FBp + 1024 + gcol);
      const float rv[4] = {bu2f(r4.x), bu2f(r4.y), bu2f(r4.z), bu2f(r4.w)};
      const float zv[4] = {bu2f(z4.x), bu2f(z4.y), bu2f(z4.z), bu2f(z4.w)};
      const float hpv[4] = {bu2f(hp4.x), bu2f(hp4.y), bu2f(hp4.z), bu2f(hp4.w)};
      const float eiv[4] = {ei.x, ei.y, ei.z, ei.w};
      const float ehv[4] = {eh.x, eh.y, eh.z, eh.w};
      const float biv[4] = {bin4.x, bin4.y, bin4.z, bin4.w};
      const float bhv[4] = {bhn4.x, bhn4.y, bhn4.z, bhn4.w};
      float vo[4];
#pragma unroll
      for (int u = 0; u < 4; ++u) {
        float rr = fsig(rv[u]);
        float zz = fsig(zv[u]);
        float nn = ftanh(eiv[u] + biv[u] + rr * (ehv[u] + bhv[u]));
        vo[u] = (1.f - zz) * nn + zz * hpv[u];
      }
      *(float4*)(Hout + (size_t)grow * 256 + gcol) =
          make_float4(vo[0], vo[1], vo[2], vo[3]);
    }
  }
}

// Canonicalize (fp32 in): weights -> bf16 blob WF, biases -> fp32 blob FB; zero BN stats.
// WF element map: fc1_w@0[65536] w_ih@65536[196608] w_hh@262144[196608]
//   W1P@458752[81920 (256x320, in1_w padded 288->320)] in2_w@540672[32768]
//   WQK@573440[8192 (128x64 [wq;wk])] wv_w@581632[20480] fc2_w@602112[10240]
// FB float map: fc1_b@0[256] BRZ@256[512 = b_ih_rz+b_hh_rz] BIN@768[256] BHN@1024[256]
//   in1_b@1280[256] in2_b@1536[128] BQK@1664[128] wv_b@1792[64] fc2_b@1856[32]
//   bn_g@1888[256] bn_b@2144[256] (gap) stats@2560[1024, zeroed]
__global__ void conv_all(
    const float* fc1_w, const float* w_ih, const float* w_hh, const float* in1_w,
    const float* in2_w, const float* wq_w, const float* wk_w, const float* wv_w,
    const float* fc2_w, const float* fc1_b, const float* b_ih, const float* b_hh,
    const float* in1_b, const float* in2_b, const float* wq_b, const float* wk_b,
    const float* wv_b, const float* fc2_b, const float* bn_g, const float* bn_b,
    bf16* __restrict__ WF, float* __restrict__ FB) {
  int idx = blockIdx.x * 256 + threadIdx.x;
  if (idx < 612352) {
    float v;
    if (idx < 65536) v = fc1_w[idx];
    else if (idx < 262144) v = w_ih[idx - 65536];
    else if (idx < 458752) v = w_hh[idx - 262144];
    else if (idx < 540672) {
      int j = idx - 458752, r = j / 320, c = j % 320;
      v = (c < 288) ? in1_w[r * 288 + c] : 0.f;
    } else if (idx < 573440) v = in2_w[idx - 540672];
    else if (idx < 581632) {
      int j = idx - 573440, r = j >> 6, c = j & 63;
      v = (r < 64) ? wq_w[r * 64 + c] : wk_w[(r - 64) * 64 + c];
    } else if (idx < 602112) v = wv_w[idx - 581632];
    else v = fc2_w[idx - 602112];
    WF[idx] = f2b(v);
  } else if (idx < 615936) {
    int j = idx - 612352;  // 0..3583
    float v;
    if (j < 256) v = fc1_b[j];
    else if (j < 768) v = b_ih[j - 256] + b_hh[j - 256];
    else if (j < 1024) v = b_ih[512 + j - 768];
    else if (j < 1280) v = b_hh[512 + j - 1024];
    else if (j < 1536) v = in1_b[j - 1280];
    else if (j < 1664) v = in2_b[j - 1536];
    else if (j < 1792) { int c = j - 1664; v = (c < 64) ? wq_b[c] : wk_b[c - 64]; }
    else if (j < 1856) v = wv_b[j - 1792];
    else if (j < 1888) v = fc2_b[j - 1856];
    else if (j < 2144) v = bn_g[j - 1888];
    else if (j < 2400) v = bn_b[j - 2144];
    else v = 0.f;  // gap + stats region zeroed
    FB[j] = v;
  }
}

// Vectorized fp32 -> bf16 copy (8 elems/thread).
__global__ void f2b_copy(const float* __restrict__ s, bf16* __restrict__ d) {
  int i = blockIdx.x * 256 + threadIdx.x;
  const float4 a = ((const float4*)s)[i * 2];
  const float4 b = ((const float4*)s)[i * 2 + 1];
  v8us o;
  o[0]=f2bu(a.x); o[1]=f2bu(a.y); o[2]=f2bu(a.z); o[3]=f2bu(a.w);
  o[4]=f2bu(b.x); o[5]=f2bu(b.y); o[6]=f2bu(b.z); o[7]=f2bu(b.w);
  ((v8us*)d)[i] = o;
}

// LAP (32768x64 bf16) = [last_actions | zeros]
__global__ void pack_la(const float* __restrict__ la, bf16* __restrict__ lap) {
  int idx = blockIdx.x * 256 + threadIdx.x;  // BN_*64
  int row = idx >> 6, c = idx & 63;
  lap[idx] = f2b((c < 32) ? la[(size_t)row * 32 + c] : 0.f);
}

__global__ void bn_reduce(const bf16* __restrict__ Z1, float* __restrict__ stats) {
  int col = threadIdx.x;
  float s = 0.f, q = 0.f;
  for (int r = blockIdx.x; r < BN_; r += 256) {
    float v = b2f(Z1[(size_t)r * 256 + col]);
    s += v; q += v * v;
  }
  atomicAdd(&stats[col], s);
  atomicAdd(&stats[256 + col], q);
}

__global__ void bn_finalize(const float* __restrict__ g, const float* __restrict__ b,
                            float* __restrict__ stats) {
  int c = threadIdx.x;
  float mean = stats[c] * (1.f / 32768.f);
  float var = stats[256 + c] * (1.f / 32768.f) - mean * mean;
  var = fmaxf(var, 0.f);
  float sc = g[c] * rsqrtf(var + 1e-5f);
  stats[512 + c] = sc;
  stats[768 + c] = b[c] - mean * sc;
}

__global__ void bn_leaky(const bf16* __restrict__ Z1, const float* __restrict__ stats,
                         bf16* __restrict__ zt) {
  int idx = blockIdx.x * 256 + threadIdx.x;
  int col = idx & 255;
  float v = b2f(Z1[idx]) * stats[512 + col] + stats[768 + col];
  zt[idx] = f2b(v > 0.f ? v : 0.01f * v);
}

__global__ void make_intent(const float* __restrict__ ie, const float* __restrict__ eps,
                            float* __restrict__ intent) {
  int idx = blockIdx.x * 256 + threadIdx.x;  // BN_*64
  int row = idx >> 6, c = idx & 63;
  float mean = ie[(size_t)row * 128 + c];
  float sd = fmaxf(expf(ie[(size_t)row * 128 + 64 + c]), 0.002f);
  intent[idx] = mean + eps[idx] * sd;
}

__global__ __launch_bounds__(64) void attn(const bf16* __restrict__ QK,
                                           const bf16* __restrict__ Vv,
                                           bf16* __restrict__ comb) {
  __shared__ float q[8][65], k[8][65], v[8][65];
  __shared__ float al[8][8];
  int b = blockIdx.x, t = threadIdx.x;
  size_t rb = (size_t)b * 8;
  for (int u = 0; u < 8; ++u) {
    q[u][t] = b2f(QK[(rb + u) * 128 + t]);
    k[u][t] = b2f(QK[(rb + u) * 128 + 64 + t]);
    v[u][t] = b2f(Vv[(rb + u) * 64 + t]);
  }
  __syncthreads();
  int i = t >> 3, j = t & 7;
  float s = 0.f;
#pragma unroll
  for (int a = 0; a < 64; ++a) s += q[i][a] * k[j][a];
  s *= 0.125f;
  if (i == j) s = -1e9f;
  float m = s;
  m = fmaxf(m, __shfl_xor(m, 1, 8));
  m = fmaxf(m, __shfl_xor(m, 2, 8));
  m = fmaxf(m, __shfl_xor(m, 4, 8));
  float e = expf(s - m);
  float sum = e;
  sum += __shfl_xor(sum, 1, 8);
  sum += __shfl_xor(sum, 2, 8);
  sum += __shfl_xor(sum, 4, 8);
  al[i][j] = e / sum;
  __syncthreads();
  int a0 = (t & 7) * 8;
  for (int u = 0; u < 8; ++u) {
    float o = 0.f;
#pragma unroll
    for (int jj = 0; jj < 8; ++jj) o += al[i][jj] * v[jj][a0 + u];
    comb[(rb + i) * 64 + a0 + u] = f2b(o);
  }
}

extern "C" void kernel_launch(void* const* d_in, const int* in_sizes, int n_in,
                              void* d_out, int out_size, void* d_ws, size_t ws_size,
                              hipStream_t stream) {
  (void)in_sizes; (void)n_in; (void)out_size; (void)ws_size;
  const float* inputs = (const float*)d_in[0];
  const float* last_actions = (const float*)d_in[1];
  const float* hidden = (const float*)d_in[2];
  const float* eps = (const float*)d_in[3];

  // d_out is FP32 (reference output dtype)
  float* out = (float*)d_out;
  float* out_lq = out;             // 32768x32
  float* out_h = out + 1048576;    // 32768x256
  float* out_it = out + 9437184;   // 32768x64
  float* out_ie = out + 11534336;  // 32768x128

  // HB = bf16(hidden), scratch in the out_ie region (dead until in2 gemm).
  bf16* HB = (bf16*)(out + 11534336);  // 16 MiB as bf16 (32768x256)

  // ---- workspace: peak ~51.6 MB ----
  char* ws = (char*)d_ws;
  bf16* X    = (bf16*)(ws + 0);            // 16 MiB, dead after gru_fused
  bf16* G1   = (bf16*)(ws + 16777216);     // 32 MiB, dead after gru_fused
  bf16* LAP  = (bf16*)(ws + 16777216);     // 4 MiB over dead G1
  bf16* ZT   = (bf16*)(ws + 20971520);     // 16 MiB over dead G1
  bf16* Z1   = (bf16*)(ws + 0);            // 16 MiB over dead X
  bf16* QK   = (bf16*)(ws + 0);            // 8 MiB over dead Z1
  bf16* V    = (bf16*)(ws + 8388608);      // 4 MiB over dead Z1
  bf16* COMB = (bf16*)(ws + 12582912);     // 4 MiB over dead Z1
  float* FB  = (float*)(ws + 50331648);    // 3584 floats @ 48 MiB mark
  bf16*  WF  = (bf16*)(ws + 50348032);     // 612352 bf16
  float* stats = FB + 2560;

  conv_all<<<2406, 256, 0, stream>>>(
      (const float*)d_in[4], (const float*)d_in[6], (const float*)d_in[7],
      (const float*)d_in[10], (const float*)d_in[14], (const float*)d_in[16],
      (const float*)d_in[18], (const float*)d_in[20], (const float*)d_in[22],
      (const float*)d_in[5], (const float*)d_in[8], (const float*)d_in[9],
      (const float*)d_in[11], (const float*)d_in[15], (const float*)d_in[17],
      (const float*)d_in[19], (const float*)d_in[21], (const float*)d_in[23],
      (const float*)d_in[12], (const float*)d_in[13], WF, FB);

  // HB = bf16(hidden)
  f2b_copy<<<4096, 256, 0, stream>>>(hidden, HB);

  // x = relu(inputs @ fc1_w^T + fc1_b)   [A fp32 -> X bf16]
  gemm_bt<128, 128, 2, 2, 1, 1, 0, 0, 0, 0><<<dim3(256, 2), 256, 0, stream>>>(
      inputs, 256, nullptr, 0, WF + 0, nullptr, 256, FB + 0, X, 256, 256);
  // G1 = [x | hb] @ [w_ih_rz | w_hh_rz]^T + (b_ih_rz + b_hh_rz)   -> bf16
  gemm_bt<128, 128, 2, 2, 0, 0, 0, 256, 256, 0><<<dim3(256, 4), 256, 0, stream>>>(
      X, 256, HB, 256, WF + 65536, WF + 262144, 256, FB + 256, G1, 512, 512);
  // out_h (fp32) = fused GRU: i_n = X@w_ihn^T, hn = HB@w_hhn^T, gates from G1
  gru_fused<<<dim3(256, 2), 256, 0, stream>>>(
      X, HB, WF + 65536 + 512 * 256, WF + 262144 + 512 * 256, FB, G1, out_h);

  pack_la<<<8192, 256, 0, stream>>>(last_actions, LAP);
  // z1 = [h(fp32) | la_pad(bf16)] @ W1P^T + in1_b   (K=320) -> Z1 bf16
  gemm_bt<128, 128, 2, 2, 0, 1, 0, 256, 0, 0><<<dim3(256, 2), 256, 0, stream>>>(
      out_h, 256, LAP, 64, WF + 458752, nullptr, 320, FB + 1280, Z1, 256, 320);
  bn_reduce<<<256, 256, 0, stream>>>(Z1, stats);
  bn_finalize<<<1, 256, 0, stream>>>(FB + 1888, FB + 2144, stats);
  bn_leaky<<<32768, 256, 0, stream>>>(Z1, stats, ZT);
  // intent_embed (fp32) = zt @ in2_w^T + in2_b
  gemm_bt<128, 128, 2, 2, 0, 0, 0, 0, 0, 1><<<dim3(256, 1), 256, 0, stream>>>(
      ZT, 256, nullptr, 0, WF + 540672, nullptr, 256, FB + 1536, out_ie, 128, 256);
  make_intent<<<8192, 256, 0, stream>>>(out_ie, eps, out_it);
  // q|k = intent(fp32) @ [wq;wk]^T -> QK bf16
  gemm_bt<128, 128, 2, 2, 0, 1, 0, 0, 0, 0><<<dim3(256, 1), 256, 0, stream>>>(
      out_it, 64, nullptr, 0, WF + 573440, nullptr, 64, FB + 1664, QK, 128, 64);
  // v = [intent(fp32) | h(fp32)] @ wv^T   (K=320) -> V bf16
  gemm_bt<128, 64, 4, 1, 0, 1, 1, 64, 0, 0><<<dim3(256, 1), 256, 0, stream>>>(
      out_it, 64, out_h, 256, WF + 581632, nullptr, 320, FB + 1792, V, 64, 320);
  attn<<<4096, 64, 0, stream>>>(QK, V, COMB);
  // local_Q (fp32) = [h(fp32) | combined(bf16)] @ fc2^T   (K=320)
  gemm_bt<128, 32, 4, 1, 0, 1, 0, 256, 0, 1><<<dim3(256, 1), 256, 0, stream>>>(
      out_h, 256, COMB, 64, WF + 602112, nullptr, 320, FB + 1856, out_lq, 32, 320);
}